// Round 3
// 787.331 us; speedup vs baseline: 1.0599x; 1.0599x over previous
//
#include <hip/hip_runtime.h>
#include <hip/hip_bf16.h>
#include <math.h>

#define BATCH 256
#define SEQ   512
#define INS   300
#define KP    320   // K padded to 10 x 32 (xg gemm)
#define HID   128
#define NG    384   // 3*HID

typedef __attribute__((ext_vector_type(8))) short short8;   // 8 x bf16 (4 VGPRs)
typedef __attribute__((ext_vector_type(4))) float f32x4;

// ---------- helpers ----------
__device__ __forceinline__ float bf2f(unsigned short u) {
    unsigned int v = ((unsigned int)u) << 16;
    return __uint_as_float(v);
}
__device__ __forceinline__ unsigned short f2bf(float f) {
    unsigned int u = __float_as_uint(f);
    unsigned int r = (u + 0x7FFFu + ((u >> 16) & 1u)) >> 16;
    return (unsigned short)r;
}

// ---------- Kernel 0: split W_ih (fp32 384x300) -> bf16 hi/lo planes (384x320, k-padded) ----------
__global__ void conv_wih(const float* __restrict__ Wih,
                         unsigned short* __restrict__ Whi,
                         unsigned short* __restrict__ Wlo)
{
    int idx = blockIdx.x * 256 + threadIdx.x;     // 0 .. 384*320-1
    if (idx >= NG * KP) return;
    int g = idx / KP, k = idx - g * KP;
    float v = (k < INS) ? Wih[g * INS + k] : 0.f;
    unsigned short h = f2bf(v);
    float r = v - bf2f(h);
    Whi[idx] = h;
    Wlo[idx] = f2bf(r);
}

// ---------- Kernel A: fused single-N-pass xg = x @ W_ih^T + b_ih ----------
// One block = 128 rows x ALL 384 cols (512 thr, 8 waves as 2M x 4N).
// x staged+split-converted ONCE (vs 3x before). B frags read directly from the
// L2-resident Whi/Wlo planes (no B LDS -> 20 KiB LDS total). Per-element MFMA
// chain order identical to previous kernel -> bitwise-identical xg.
template <bool BF16OUT>
__launch_bounds__(512, 2)
__global__ void xg_fused(const float* __restrict__ x,
                         const unsigned short* __restrict__ Whi,
                         const unsigned short* __restrict__ Wlo,
                         const float* __restrict__ bih,
                         void* __restrict__ xg_out,
                         int t0, int CT)
{
    __shared__ unsigned short Ah[128][40], Al[128][40];   // 20 KiB, +8 pad: conflict-free b128 reads

    const int tid  = threadIdx.x;
    const int lane = tid & 63;
    const int w    = tid >> 6;          // 0..7
    const int wm   = (w & 1) * 64;      // M half
    const int wn   = (w >> 1) * 96;     // N quarter
    const int m0   = blockIdx.x * 128;

    // A staging: thread -> (row, 8-k chunk)
    const int srow = tid >> 2;          // 0..127
    const int kq   = tid & 3;           // 0..3
    const int rr = m0 + srow;
    const int bb = rr / CT;
    const float* xrow = x + (size_t)(bb * SEQ + t0 + (rr - bb * CT)) * INS;

    const int lmf = lane & 15;
    const int lk  = (lane >> 4) * 8;

    f32x4 acc[4][6] = {};

    float av[8];
    auto loadA = [&](int ks) {
        const int k0 = ks * 32 + kq * 8;
        if (k0 + 8 <= INS) {
            float4 f0 = *(const float4*)(xrow + k0);
            float4 f1 = *(const float4*)(xrow + k0 + 4);
            av[0] = f0.x; av[1] = f0.y; av[2] = f0.z; av[3] = f0.w;
            av[4] = f1.x; av[5] = f1.y; av[6] = f1.z; av[7] = f1.w;
        } else {
            #pragma unroll
            for (int i = 0; i < 8; i++)
                av[i] = (k0 + i < INS) ? xrow[k0 + i] : 0.f;
        }
    };
    loadA(0);

    for (int ks = 0; ks < KP / 32; ks++) {
        // B frags for this k-slab: issue early, straight from global (L2-hot).
        short8 bh[6], bl[6];
        #pragma unroll
        for (int ni = 0; ni < 6; ni++) {
            const size_t off = (size_t)(wn + ni * 16 + lmf) * KP + ks * 32 + lk;
            bh[ni] = *(const short8*)(Whi + off);
            bl[ni] = *(const short8*)(Wlo + off);
        }

        __syncthreads();   // prev k-step's A-frag reads done; safe to overwrite
        {
            union { unsigned short us[8]; uint4 q; } ph, pl;
            #pragma unroll
            for (int i = 0; i < 8; i++) {
                unsigned short h = f2bf(av[i]);
                ph.us[i] = h;
                pl.us[i] = f2bf(av[i] - bf2f(h));
            }
            *(uint4*)&Ah[srow][kq * 8] = ph.q;
            *(uint4*)&Al[srow][kq * 8] = pl.q;
        }
        if (ks + 1 < KP / 32) loadA(ks + 1);   // T14: issue next slab before barrier
        __syncthreads();

        short8 ah[4], al[4];
        #pragma unroll
        for (int mi = 0; mi < 4; mi++) {
            ah[mi] = *(const short8*)&Ah[wm + mi * 16 + lmf][lk];
            al[mi] = *(const short8*)&Al[wm + mi * 16 + lmf][lk];
        }
        #pragma unroll
        for (int ni = 0; ni < 6; ni++) {
            #pragma unroll
            for (int mi = 0; mi < 4; mi++) {
                acc[mi][ni] = __builtin_amdgcn_mfma_f32_16x16x32_bf16(ah[mi], bh[ni], acc[mi][ni], 0, 0, 0);
                acc[mi][ni] = __builtin_amdgcn_mfma_f32_16x16x32_bf16(ah[mi], bl[ni], acc[mi][ni], 0, 0, 0);
                acc[mi][ni] = __builtin_amdgcn_mfma_f32_16x16x32_bf16(al[mi], bh[ni], acc[mi][ni], 0, 0, 0);
            }
        }
    }

    const int crow = (lane >> 4) * 4;
    #pragma unroll
    for (int ni = 0; ni < 6; ni++) {
        const int col = wn + ni * 16 + lmf;
        const float bias = bih[col];
        #pragma unroll
        for (int mi = 0; mi < 4; mi++) {
            #pragma unroll
            for (int i = 0; i < 4; i++) {
                const size_t row = (size_t)(m0 + wm + mi * 16 + crow + i);
                const float val = acc[mi][ni][i] + bias;
                if (BF16OUT) ((unsigned short*)xg_out)[row * NG + col] = f2bf(val);
                else         ((float*)xg_out)[row * NG + col] = val;
            }
        }
    }
}

// ---------- Kernel B: MFMA recurrence, pass-folded into A rows ----------
// A row 0 = h_hi, row 1 = h_lo (rows 2-15 = harmless h_hi dups). One MFMA vs
// W_hi yields hh*Wh (reg0) AND hl*Wh (reg1); a second vs W_lo yields hh*Wl.
// 3 split-precision products in 2 MFMAs -> 48 MFMA/wave/step (was 72).
// Products + accumulation order bitwise-identical to previous kernel.
template <bool BF16XG>
__launch_bounds__(256, 1)
__global__ void gru_mfma(const void* __restrict__ xg_in,
                         const float* __restrict__ Whh,
                         const float* __restrict__ bhh,
                         float* __restrict__ hstate,
                         int t0, int CT, int initial, int final_chunk,
                         const float* __restrict__ Wout,
                         const float* __restrict__ bout,
                         float* __restrict__ out)
{
    const int b    = blockIdx.x;
    const int tid  = threadIdx.x;
    const int w    = tid >> 6;
    const int lane = tid & 63;
    const int lm   = lane & 15;
    const int quad = lane >> 4;

    __shared__ alignas(16) unsigned short hbuf[2][2][HID];  // [dbuf][hi/lo][j], 1 KiB
    __shared__ float red[2 * HID];

    // wave w's N-tiles (16 gate-cols each): r: {2w,2w+1}, z: {8+2w,..}, n: {16+2w,..}
    const int mt0 = 2 * w, mt2 = 8 + 2 * w, mt4 = 16 + 2 * w;
    const int mts[6] = {mt0, mt0 + 1, mt2, mt2 + 1, mt4, mt4 + 1};

    // ---- persistent B fragments: B[k=32kt+quad*8+j][n=tile*16+lm] = Whh[n][k] ----
    short8 w_hi[6][4], w_lo[6][4];
    #pragma unroll
    for (int t = 0; t < 6; t++) {
        const float* wrow = Whh + (size_t)(mts[t] * 16 + lm) * HID + quad * 8;
        #pragma unroll
        for (int kt = 0; kt < 4; kt++) {
            float4 f0 = *(const float4*)(wrow + kt * 32);
            float4 f1 = *(const float4*)(wrow + kt * 32 + 4);
            float vv[8] = {f0.x, f0.y, f0.z, f0.w, f1.x, f1.y, f1.z, f1.w};
            short8 h8, l8;
            #pragma unroll
            for (int i = 0; i < 8; i++) {
                unsigned short h = f2bf(vv[i]);
                h8[i] = (short)h;
                l8[i] = (short)f2bf(vv[i] - bf2f(h));
            }
            w_hi[t][kt] = h8;
            w_lo[t][kt] = l8;
        }
    }

    // ---- per-activation-lane state: lanes 0-15 own j = 32w + 16d + lm, d=0,1 ----
    float hprev[2] = {0.f, 0.f};
    float bhr[2] = {}, bhz[2] = {}, bhn[2] = {};
    float wo0[2] = {}, wo1[2] = {};
    float nxr[2] = {}, nxz[2] = {}, nxn[2] = {};
    const float* xgf = (const float*)xg_in;
    const unsigned short* xgb = (const unsigned short*)xg_in;

    if (lane < 16) {
        #pragma unroll
        for (int d = 0; d < 2; d++) {
            const int jd = w * 32 + 16 * d + lm;
            float h0 = initial ? 0.f : hstate[b * HID + jd];
            hprev[d] = h0;
            bhr[d] = bhh[jd]; bhz[d] = bhh[HID + jd]; bhn[d] = bhh[2 * HID + jd];
            wo0[d] = Wout[jd]; wo1[d] = Wout[HID + jd];
            unsigned short hh = f2bf(h0);
            hbuf[0][0][jd] = hh;
            hbuf[0][1][jd] = f2bf(h0 - bf2f(hh));
            const size_t nb = (size_t)b * CT * NG;
            if (BF16XG) { nxr[d] = bf2f(xgb[nb + jd]); nxz[d] = bf2f(xgb[nb + HID + jd]); nxn[d] = bf2f(xgb[nb + 2 * HID + jd]); }
            else        { nxr[d] = xgf[nb + jd];       nxz[d] = xgf[nb + HID + jd];       nxn[d] = xgf[nb + 2 * HID + jd]; }
        }
    }
    __syncthreads();

    // A-frag plane select: row (=lm) 0 reads h_hi, row 1 reads h_lo, rows 2-15 h_hi dups
    const int psel = (lm == 1) ? 1 : 0;

    for (int tt = 0; tt < CT; tt++) {
        const int p = tt & 1;
        short8 a2[4];
        #pragma unroll
        for (int kt = 0; kt < 4; kt++)
            a2[kt] = *(const short8*)&hbuf[p][psel][kt * 32 + quad * 8];

        // ---- 12 independent depth-4 MFMA chains (was 18) ----
        f32x4 c1[6] = {}, c2[6] = {};
        #pragma unroll
        for (int kt = 0; kt < 4; kt++) {
            #pragma unroll
            for (int t = 0; t < 6; t++)
                c1[t] = __builtin_amdgcn_mfma_f32_16x16x32_bf16(a2[kt], w_hi[t][kt], c1[t], 0, 0, 0);
            #pragma unroll
            for (int t = 0; t < 6; t++)
                c2[t] = __builtin_amdgcn_mfma_f32_16x16x32_bf16(a2[kt], w_lo[t][kt], c2[t], 0, 0, 0);
        }

        // ---- activation: lanes 0-15 (quad 0) hold rows 0,1 in regs 0,1 ----
        if (lane < 16) {
            #pragma unroll
            for (int d = 0; d < 2; d++) {
                const int jd = w * 32 + 16 * d + lm;
                // (hh + lh) + hl  + bias  -- same order as before
                float hgr = (c1[0 + d][0] + c1[0 + d][1]) + c2[0 + d][0] + bhr[d];
                float hgz = (c1[2 + d][0] + c1[2 + d][1]) + c2[2 + d][0] + bhz[d];
                float hgn = (c1[4 + d][0] + c1[4 + d][1]) + c2[4 + d][0] + bhn[d];
                float rg = 1.f / (1.f + __expf(-(nxr[d] + hgr)));
                float zg = 1.f / (1.f + __expf(-(nxz[d] + hgz)));
                float nv = nxn[d] + rg * hgn;
                float e  = __expf(2.f * nv);
                float ng = 1.f - 2.f / (e + 1.f);
                float hn2 = (1.f - zg) * ng + zg * hprev[d];
                hprev[d] = hn2;
                unsigned short hh = f2bf(hn2);
                hbuf[1 - p][0][jd] = hh;
                hbuf[1 - p][1][jd] = f2bf(hn2 - bf2f(hh));
                if (tt + 1 < CT) {   // prefetch next xg; stays in flight across barrier
                    const size_t nb = ((size_t)b * CT + tt + 1) * NG;
                    if (BF16XG) { nxr[d] = bf2f(xgb[nb + jd]); nxz[d] = bf2f(xgb[nb + HID + jd]); nxn[d] = bf2f(xgb[nb + 2 * HID + jd]); }
                    else        { nxr[d] = xgf[nb + jd];       nxz[d] = xgf[nb + HID + jd];       nxn[d] = xgf[nb + 2 * HID + jd]; }
                }
            }
        }
        // drain LDS writes only (not vmcnt), then barrier
        asm volatile("s_waitcnt lgkmcnt(0)\ns_barrier" ::: "memory");
    }

    if (lane < 16) {
        #pragma unroll
        for (int d = 0; d < 2; d++)
            hstate[b * HID + (w * 32 + 16 * d + lm)] = hprev[d];
    }

    // ---- head: relu -> 2-class linear -> log_softmax (identical reduction tree) ----
    if (final_chunk) {
        if (lane < 16) {
            #pragma unroll
            for (int d = 0; d < 2; d++) {
                const int jd = w * 32 + 16 * d + lm;
                float f = hprev[d] > 0.f ? hprev[d] : 0.f;
                red[jd] = f * wo0[d];
                red[HID + jd] = f * wo1[d];
            }
        }
        __syncthreads();
        if (tid < 64) {
            float l0 = red[tid] + red[64 + tid];
            float l1 = red[HID + tid] + red[HID + 64 + tid];
            #pragma unroll
            for (int d = 32; d > 0; d >>= 1) {
                l0 += __shfl_down(l0, d, 64);
                l1 += __shfl_down(l1, d, 64);
            }
            if (tid == 0) {
                l0 += bout[0]; l1 += bout[1];
                float m = fmaxf(l0, l1);
                float lse = m + logf(__expf(l0 - m) + __expf(l1 - m));
                out[b * 2 + 0] = l0 - lse;
                out[b * 2 + 1] = l1 - lse;
            }
        }
    }
}

// ---------- launch ----------
extern "C" void kernel_launch(void* const* d_in, const int* in_sizes, int n_in,
                              void* d_out, int out_size, void* d_ws, size_t ws_size,
                              hipStream_t stream) {
    const float* x    = (const float*)d_in[0];
    const float* Wih  = (const float*)d_in[1];
    const float* Whh  = (const float*)d_in[2];
    const float* bih  = (const float*)d_in[3];
    const float* bhh  = (const float*)d_in[4];
    const float* Wout = (const float*)d_in[5];
    const float* bout = (const float*)d_in[6];
    float* out = (float*)d_out;

    // ws layout: [W_hi | W_lo | hstate | xg]
    unsigned short* Whi = (unsigned short*)d_ws;                       // 384*320*2 = 245760 B
    unsigned short* Wlo = (unsigned short*)((char*)d_ws + 245760);
    float* hstate = (float*)((char*)d_ws + 491520);                    // 128 KiB
    void*  xg     = (void*)((char*)d_ws + 622592);
    const size_t avail = ws_size > 622592 ? ws_size - 622592 : 0;

    bool bf16;
    int CT;
    if (avail >= (size_t)BATCH * SEQ * NG * 4) {        // fp32 xg (201 MB)
        bf16 = false; CT = SEQ;
    } else if (avail >= (size_t)BATCH * SEQ * NG * 2) { // bf16 xg (100 MB)
        bf16 = true;  CT = SEQ;
    } else {                                            // chunked bf16
        bf16 = true;
        CT = 64;
        while (CT * 2 <= SEQ && avail >= (size_t)BATCH * (size_t)(CT * 2) * NG * 2) CT *= 2;
    }

    conv_wih<<<(NG * KP + 255) / 256, 256, 0, stream>>>(Wih, Whi, Wlo);

    for (int t0 = 0; t0 < SEQ; t0 += CT) {
        dim3 gridA((BATCH * CT) / 128);
        const int initial = (t0 == 0);
        const int final_chunk = (t0 + CT >= SEQ);
        if (bf16) {
            xg_fused<true><<<gridA, 512, 0, stream>>>(x, Whi, Wlo, bih, xg, t0, CT);
            gru_mfma<true><<<BATCH, 256, 0, stream>>>(xg, Whh, bhh, hstate, t0, CT,
                                                      initial, final_chunk, Wout, bout, out);
        } else {
            xg_fused<false><<<gridA, 512, 0, stream>>>(x, Whi, Wlo, bih, xg, t0, CT);
            gru_mfma<false><<<BATCH, 256, 0, stream>>>(xg, Whh, bhh, hstate, t0, CT,
                                                       initial, final_chunk, Wout, bout, out);
        }
    }
}

// Round 4
// 700.023 us; speedup vs baseline: 1.1921x; 1.1247x over previous
//
#include <hip/hip_runtime.h>
#include <hip/hip_bf16.h>
#include <math.h>

#define BATCH 256
#define SEQ   512
#define INS   300
#define KP    320   // K padded to 10 x 32 (xg gemm)
#define HID   128
#define NG    384   // 3*HID

typedef __attribute__((ext_vector_type(8))) short short8;   // 8 x bf16 (4 VGPRs)
typedef __attribute__((ext_vector_type(4))) float f32x4;

// ---------- helpers ----------
__device__ __forceinline__ float bf2f(unsigned short u) {
    unsigned int v = ((unsigned int)u) << 16;
    return __uint_as_float(v);
}
__device__ __forceinline__ unsigned short f2bf(float f) {
    unsigned int u = __float_as_uint(f);
    unsigned int r = (u + 0x7FFFu + ((u >> 16) & 1u)) >> 16;
    return (unsigned short)r;
}

// ---------- Kernel 0: split W_ih (fp32 384x300) -> bf16 hi/lo planes (384x320, k-padded) ----------
__global__ void conv_wih(const float* __restrict__ Wih,
                         unsigned short* __restrict__ Whi,
                         unsigned short* __restrict__ Wlo)
{
    int idx = blockIdx.x * 256 + threadIdx.x;     // 0 .. 384*320-1
    if (idx >= NG * KP) return;
    int g = idx / KP, k = idx - g * KP;
    float v = (k < INS) ? Wih[g * INS + k] : 0.f;
    unsigned short h = f2bf(v);
    float r = v - bf2f(h);
    Whi[idx] = h;
    Wlo[idx] = f2bf(r);
}

// ---------- Kernel A: fused single-N-pass xg = x @ W_ih^T + b_ih (unchanged) ----------
template <bool BF16OUT>
__launch_bounds__(512, 2)
__global__ void xg_fused(const float* __restrict__ x,
                         const unsigned short* __restrict__ Whi,
                         const unsigned short* __restrict__ Wlo,
                         const float* __restrict__ bih,
                         void* __restrict__ xg_out,
                         int t0, int CT)
{
    __shared__ unsigned short Ah[128][40], Al[128][40];   // 20 KiB

    const int tid  = threadIdx.x;
    const int lane = tid & 63;
    const int w    = tid >> 6;          // 0..7
    const int wm   = (w & 1) * 64;      // M half
    const int wn   = (w >> 1) * 96;     // N quarter
    const int m0   = blockIdx.x * 128;

    const int srow = tid >> 2;          // 0..127
    const int kq   = tid & 3;           // 0..3
    const int rr = m0 + srow;
    const int bb = rr / CT;
    const float* xrow = x + (size_t)(bb * SEQ + t0 + (rr - bb * CT)) * INS;

    const int lmf = lane & 15;
    const int lk  = (lane >> 4) * 8;

    f32x4 acc[4][6] = {};

    float av[8];
    auto loadA = [&](int ks) {
        const int k0 = ks * 32 + kq * 8;
        if (k0 + 8 <= INS) {
            float4 f0 = *(const float4*)(xrow + k0);
            float4 f1 = *(const float4*)(xrow + k0 + 4);
            av[0] = f0.x; av[1] = f0.y; av[2] = f0.z; av[3] = f0.w;
            av[4] = f1.x; av[5] = f1.y; av[6] = f1.z; av[7] = f1.w;
        } else {
            #pragma unroll
            for (int i = 0; i < 8; i++)
                av[i] = (k0 + i < INS) ? xrow[k0 + i] : 0.f;
        }
    };
    loadA(0);

    for (int ks = 0; ks < KP / 32; ks++) {
        short8 bh[6], bl[6];
        #pragma unroll
        for (int ni = 0; ni < 6; ni++) {
            const size_t off = (size_t)(wn + ni * 16 + lmf) * KP + ks * 32 + lk;
            bh[ni] = *(const short8*)(Whi + off);
            bl[ni] = *(const short8*)(Wlo + off);
        }

        __syncthreads();
        {
            union { unsigned short us[8]; uint4 q; } ph, pl;
            #pragma unroll
            for (int i = 0; i < 8; i++) {
                unsigned short h = f2bf(av[i]);
                ph.us[i] = h;
                pl.us[i] = f2bf(av[i] - bf2f(h));
            }
            *(uint4*)&Ah[srow][kq * 8] = ph.q;
            *(uint4*)&Al[srow][kq * 8] = pl.q;
        }
        if (ks + 1 < KP / 32) loadA(ks + 1);
        __syncthreads();

        short8 ah[4], al[4];
        #pragma unroll
        for (int mi = 0; mi < 4; mi++) {
            ah[mi] = *(const short8*)&Ah[wm + mi * 16 + lmf][lk];
            al[mi] = *(const short8*)&Al[wm + mi * 16 + lmf][lk];
        }
        #pragma unroll
        for (int ni = 0; ni < 6; ni++) {
            #pragma unroll
            for (int mi = 0; mi < 4; mi++) {
                acc[mi][ni] = __builtin_amdgcn_mfma_f32_16x16x32_bf16(ah[mi], bh[ni], acc[mi][ni], 0, 0, 0);
                acc[mi][ni] = __builtin_amdgcn_mfma_f32_16x16x32_bf16(ah[mi], bl[ni], acc[mi][ni], 0, 0, 0);
                acc[mi][ni] = __builtin_amdgcn_mfma_f32_16x16x32_bf16(al[mi], bh[ni], acc[mi][ni], 0, 0, 0);
            }
        }
    }

    const int crow = (lane >> 4) * 4;
    #pragma unroll
    for (int ni = 0; ni < 6; ni++) {
        const int col = wn + ni * 16 + lmf;
        const float bias = bih[col];
        #pragma unroll
        for (int mi = 0; mi < 4; mi++) {
            #pragma unroll
            for (int i = 0; i < 4; i++) {
                const size_t row = (size_t)(m0 + wm + mi * 16 + crow + i);
                const float val = acc[mi][ni][i] + bias;
                if (BF16OUT) ((unsigned short*)xg_out)[row * NG + col] = f2bf(val);
                else         ((float*)xg_out)[row * NG + col] = val;
            }
        }
    }
}

// ---------- Kernel B: MFMA recurrence ----------
// Pass-folded A rows: rows with (lm&3)==1 carry h_lo, all others h_hi.
// => EVERY quad's C regs 0/1 = (hh*W, hl*W) for its col => activation spread
// across lanes 0-31 (quad0: d=0, quad1: d=1), one column per lane.
// hbuf planes padded to 320B stride so lo-plane reads land in the opposite
// 16-bank half from hi reads (kills the 8.4M conflict cycles of r3).
// tt-loop unrolled x2: compile-time double-buffer index + xg prefetch
// distance 2 (covers cold-HBM latency of the per-step xg loads).
// Product set + accumulation order bitwise-identical to r3.
template <bool BF16XG>
__launch_bounds__(256, 1)
__global__ void gru_mfma(const void* __restrict__ xg_in,
                         const float* __restrict__ Whh,
                         const float* __restrict__ bhh,
                         float* __restrict__ hstate,
                         int t0, int CT, int initial, int final_chunk,
                         const float* __restrict__ Wout,
                         const float* __restrict__ bout,
                         float* __restrict__ out)
{
    const int b    = blockIdx.x;
    const int tid  = threadIdx.x;
    const int w    = tid >> 6;
    const int lane = tid & 63;
    const int lm   = lane & 15;
    const int quad = lane >> 4;

    __shared__ alignas(16) unsigned short hbuf[2][2][160]; // [dbuf][hi/lo][j], 320B plane stride
    __shared__ float red[2 * HID];

    // wave w's N-tiles (16 gate-cols each): r: {2w,2w+1}, z: {8+2w,..}, n: {16+2w,..}
    const int mt0 = 2 * w, mt2 = 8 + 2 * w, mt4 = 16 + 2 * w;
    const int mts[6] = {mt0, mt0 + 1, mt2, mt2 + 1, mt4, mt4 + 1};

    // ---- persistent B fragments: B[k=32kt+quad*8+j][n=tile*16+lm] = Whh[n][k] ----
    short8 w_hi[6][4], w_lo[6][4];
    #pragma unroll
    for (int t = 0; t < 6; t++) {
        const float* wrow = Whh + (size_t)(mts[t] * 16 + lm) * HID + quad * 8;
        #pragma unroll
        for (int kt = 0; kt < 4; kt++) {
            float4 f0 = *(const float4*)(wrow + kt * 32);
            float4 f1 = *(const float4*)(wrow + kt * 32 + 4);
            float vv[8] = {f0.x, f0.y, f0.z, f0.w, f1.x, f1.y, f1.z, f1.w};
            short8 h8, l8;
            #pragma unroll
            for (int i = 0; i < 8; i++) {
                unsigned short h = f2bf(vv[i]);
                h8[i] = (short)h;
                l8[i] = (short)f2bf(vv[i] - bf2f(h));
            }
            w_hi[t][kt] = h8;
            w_lo[t][kt] = l8;
        }
    }

    // ---- per-activation-lane state: lanes 0-31 own jd = 32w + 16*quad + lm ----
    const int dq = quad & 1;                    // d index for lanes<32
    const int jd = w * 32 + 16 * dq + lm;
    float hprev = 0.f, bhr = 0.f, bhz = 0.f, bhn = 0.f, wo0 = 0.f, wo1 = 0.f;
    float nx0r = 0.f, nx0z = 0.f, nx0n = 0.f;   // xg for even steps
    float nx1r = 0.f, nx1z = 0.f, nx1n = 0.f;   // xg for odd steps
    const float* xgf = (const float*)xg_in;
    const unsigned short* xgb = (const unsigned short*)xg_in;

    if (lane < 32) {
        float h0 = initial ? 0.f : hstate[b * HID + jd];
        hprev = h0;
        bhr = bhh[jd]; bhz = bhh[HID + jd]; bhn = bhh[2 * HID + jd];
        wo0 = Wout[jd]; wo1 = Wout[HID + jd];
        unsigned short hh = f2bf(h0);
        hbuf[0][0][jd] = hh;
        hbuf[0][1][jd] = f2bf(h0 - bf2f(hh));
        const size_t nb0 = (size_t)b * CT * NG;
        const size_t nb1 = nb0 + NG;
        if (BF16XG) {
            nx0r = bf2f(xgb[nb0 + jd]); nx0z = bf2f(xgb[nb0 + HID + jd]); nx0n = bf2f(xgb[nb0 + 2 * HID + jd]);
            nx1r = bf2f(xgb[nb1 + jd]); nx1z = bf2f(xgb[nb1 + HID + jd]); nx1n = bf2f(xgb[nb1 + 2 * HID + jd]);
        } else {
            nx0r = xgf[nb0 + jd]; nx0z = xgf[nb0 + HID + jd]; nx0n = xgf[nb0 + 2 * HID + jd];
            nx1r = xgf[nb1 + jd]; nx1z = xgf[nb1 + HID + jd]; nx1n = xgf[nb1 + 2 * HID + jd];
        }
    }
    __syncthreads();

    // A-frag plane select: rows lm in {1,5,9,13} read h_lo, others h_hi
    const int psel = ((lm & 3) == 1) ? 1 : 0;

// one GRU timestep; P = compile-time dbuf index, T = runtime step, NX* = its xg regs
#define GRU_STEP(P, T, NXR, NXZ, NXN)                                                             \
    {                                                                                             \
        short8 a2[4];                                                                             \
        _Pragma("unroll")                                                                         \
        for (int kt = 0; kt < 4; kt++)                                                            \
            a2[kt] = *(const short8*)&hbuf[P][psel][kt * 32 + quad * 8];                          \
        f32x4 c1[6] = {}, c2[6] = {};                                                             \
        _Pragma("unroll")                                                                         \
        for (int kt = 0; kt < 4; kt++) {                                                          \
            _Pragma("unroll")                                                                     \
            for (int t = 0; t < 6; t++)                                                           \
                c1[t] = __builtin_amdgcn_mfma_f32_16x16x32_bf16(a2[kt], w_hi[t][kt], c1[t], 0, 0, 0); \
            _Pragma("unroll")                                                                     \
            for (int t = 0; t < 6; t++)                                                           \
                c2[t] = __builtin_amdgcn_mfma_f32_16x16x32_bf16(a2[kt], w_lo[t][kt], c2[t], 0, 0, 0); \
        }                                                                                         \
        if (lane < 32) {                                                                          \
            /* per-tile merged sums, same add order as before: (hh+lh)+hl */                      \
            float s0 = (c1[0][0] + c1[0][1]) + c2[0][0];                                          \
            float s1 = (c1[1][0] + c1[1][1]) + c2[1][0];                                          \
            float s2 = (c1[2][0] + c1[2][1]) + c2[2][0];                                          \
            float s3 = (c1[3][0] + c1[3][1]) + c2[3][0];                                          \
            float s4 = (c1[4][0] + c1[4][1]) + c2[4][0];                                          \
            float s5 = (c1[5][0] + c1[5][1]) + c2[5][0];                                          \
            float hgr = (dq ? s1 : s0) + bhr;                                                     \
            float hgz = (dq ? s3 : s2) + bhz;                                                     \
            float hgn = (dq ? s5 : s4) + bhn;                                                     \
            float rg = 1.f / (1.f + __expf(-((NXR) + hgr)));                                      \
            float zg = 1.f / (1.f + __expf(-((NXZ) + hgz)));                                      \
            float nv = (NXN) + rg * hgn;                                                          \
            float e  = __expf(2.f * nv);                                                          \
            float ng = 1.f - 2.f / (e + 1.f);                                                     \
            hprev = (1.f - zg) * ng + zg * hprev;                                                 \
            unsigned short hh = f2bf(hprev);                                                      \
            hbuf[1 - (P)][0][jd] = hh;                                                            \
            hbuf[1 - (P)][1][jd] = f2bf(hprev - bf2f(hh));                                        \
            if ((T) + 2 < CT) {   /* prefetch distance 2; stays in flight across barriers */      \
                const size_t nb = ((size_t)b * CT + (T) + 2) * NG;                                \
                if (BF16XG) { NXR = bf2f(xgb[nb + jd]); NXZ = bf2f(xgb[nb + HID + jd]); NXN = bf2f(xgb[nb + 2 * HID + jd]); } \
                else        { NXR = xgf[nb + jd];       NXZ = xgf[nb + HID + jd];       NXN = xgf[nb + 2 * HID + jd]; }       \
            }                                                                                     \
        }                                                                                         \
        asm volatile("s_waitcnt lgkmcnt(0)\ns_barrier" ::: "memory");                             \
    }

    for (int tt = 0; tt < CT; tt += 2) {      // CT is a power of two >= 64
        GRU_STEP(0, tt,     nx0r, nx0z, nx0n)
        GRU_STEP(1, tt + 1, nx1r, nx1z, nx1n)
    }
#undef GRU_STEP

    if (lane < 32) hstate[b * HID + jd] = hprev;

    // ---- head: relu -> 2-class linear -> log_softmax (identical reduction tree) ----
    if (final_chunk) {
        if (lane < 32) {
            float f = hprev > 0.f ? hprev : 0.f;
            red[jd] = f * wo0;
            red[HID + jd] = f * wo1;
        }
        __syncthreads();
        if (tid < 64) {
            float l0 = red[tid] + red[64 + tid];
            float l1 = red[HID + tid] + red[HID + 64 + tid];
            #pragma unroll
            for (int d = 32; d > 0; d >>= 1) {
                l0 += __shfl_down(l0, d, 64);
                l1 += __shfl_down(l1, d, 64);
            }
            if (tid == 0) {
                l0 += bout[0]; l1 += bout[1];
                float m = fmaxf(l0, l1);
                float lse = m + logf(__expf(l0 - m) + __expf(l1 - m));
                out[b * 2 + 0] = l0 - lse;
                out[b * 2 + 1] = l1 - lse;
            }
        }
    }
}

// ---------- launch ----------
extern "C" void kernel_launch(void* const* d_in, const int* in_sizes, int n_in,
                              void* d_out, int out_size, void* d_ws, size_t ws_size,
                              hipStream_t stream) {
    const float* x    = (const float*)d_in[0];
    const float* Wih  = (const float*)d_in[1];
    const float* Whh  = (const float*)d_in[2];
    const float* bih  = (const float*)d_in[3];
    const float* bhh  = (const float*)d_in[4];
    const float* Wout = (const float*)d_in[5];
    const float* bout = (const float*)d_in[6];
    float* out = (float*)d_out;

    // ws layout: [W_hi | W_lo | hstate | xg]
    unsigned short* Whi = (unsigned short*)d_ws;                       // 384*320*2 = 245760 B
    unsigned short* Wlo = (unsigned short*)((char*)d_ws + 245760);
    float* hstate = (float*)((char*)d_ws + 491520);                    // 128 KiB
    void*  xg     = (void*)((char*)d_ws + 622592);
    const size_t avail = ws_size > 622592 ? ws_size - 622592 : 0;

    bool bf16;
    int CT;
    if (avail >= (size_t)BATCH * SEQ * NG * 4) {        // fp32 xg (201 MB)
        bf16 = false; CT = SEQ;
    } else if (avail >= (size_t)BATCH * SEQ * NG * 2) { // bf16 xg (100 MB)
        bf16 = true;  CT = SEQ;
    } else {                                            // chunked bf16
        bf16 = true;
        CT = 64;
        while (CT * 2 <= SEQ && avail >= (size_t)BATCH * (size_t)(CT * 2) * NG * 2) CT *= 2;
    }

    conv_wih<<<(NG * KP + 255) / 256, 256, 0, stream>>>(Wih, Whi, Wlo);

    for (int t0 = 0; t0 < SEQ; t0 += CT) {
        dim3 gridA((BATCH * CT) / 128);
        const int initial = (t0 == 0);
        const int final_chunk = (t0 + CT >= SEQ);
        if (bf16) {
            xg_fused<true><<<gridA, 512, 0, stream>>>(x, Whi, Wlo, bih, xg, t0, CT);
            gru_mfma<true><<<BATCH, 256, 0, stream>>>(xg, Whh, bhh, hstate, t0, CT,
                                                      initial, final_chunk, Wout, bout, out);
        } else {
            xg_fused<false><<<gridA, 512, 0, stream>>>(x, Whi, Wlo, bih, xg, t0, CT);
            gru_mfma<false><<<BATCH, 256, 0, stream>>>(xg, Whh, bhh, hstate, t0, CT,
                                                       initial, final_chunk, Wout, bout, out);
        }
    }
}

// Round 6
// 651.677 us; speedup vs baseline: 1.2805x; 1.0742x over previous
//
#include <hip/hip_runtime.h>
#include <hip/hip_bf16.h>
#include <math.h>

#define BATCH 256
#define SEQ   512
#define INS   300
#define KP    320   // K padded to 10 x 32 (xg gemm)
#define HID   128
#define NG    384   // 3*HID

typedef __attribute__((ext_vector_type(8))) short short8;   // 8 x bf16 (4 VGPRs)
typedef __attribute__((ext_vector_type(4))) float f32x4;

// ---------- helpers ----------
__device__ __forceinline__ float bf2f(unsigned short u) {
    unsigned int v = ((unsigned int)u) << 16;
    return __uint_as_float(v);
}
__device__ __forceinline__ unsigned short f2bf(float f) {
    unsigned int u = __float_as_uint(f);
    unsigned int r = (u + 0x7FFFu + ((u >> 16) & 1u)) >> 16;
    return (unsigned short)r;
}

// ---------- Kernel 0: split W_ih (fp32 384x300) -> bf16 hi/lo planes (384x320, k-padded) ----------
__global__ void conv_wih(const float* __restrict__ Wih,
                         unsigned short* __restrict__ Whi,
                         unsigned short* __restrict__ Wlo)
{
    int idx = blockIdx.x * 256 + threadIdx.x;     // 0 .. 384*320-1
    if (idx >= NG * KP) return;
    int g = idx / KP, k = idx - g * KP;
    float v = (k < INS) ? Wih[g * INS + k] : 0.f;
    unsigned short h = f2bf(v);
    float r = v - bf2f(h);
    Whi[idx] = h;
    Wlo[idx] = f2bf(r);
}

// ---------- Kernel A: fused single-N-pass xg = x @ W_ih^T + b_ih (unchanged) ----------
template <bool BF16OUT>
__launch_bounds__(512, 2)
__global__ void xg_fused(const float* __restrict__ x,
                         const unsigned short* __restrict__ Whi,
                         const unsigned short* __restrict__ Wlo,
                         const float* __restrict__ bih,
                         void* __restrict__ xg_out,
                         int t0, int CT)
{
    __shared__ unsigned short Ah[128][40], Al[128][40];   // 20 KiB

    const int tid  = threadIdx.x;
    const int lane = tid & 63;
    const int w    = tid >> 6;          // 0..7
    const int wm   = (w & 1) * 64;      // M half
    const int wn   = (w >> 1) * 96;     // N quarter
    const int m0   = blockIdx.x * 128;

    const int srow = tid >> 2;          // 0..127
    const int kq   = tid & 3;           // 0..3
    const int rr = m0 + srow;
    const int bb = rr / CT;
    const float* xrow = x + (size_t)(bb * SEQ + t0 + (rr - bb * CT)) * INS;

    const int lmf = lane & 15;
    const int lk  = (lane >> 4) * 8;

    f32x4 acc[4][6] = {};

    float av[8];
    auto loadA = [&](int ks) {
        const int k0 = ks * 32 + kq * 8;
        if (k0 + 8 <= INS) {
            float4 f0 = *(const float4*)(xrow + k0);
            float4 f1 = *(const float4*)(xrow + k0 + 4);
            av[0] = f0.x; av[1] = f0.y; av[2] = f0.z; av[3] = f0.w;
            av[4] = f1.x; av[5] = f1.y; av[6] = f1.z; av[7] = f1.w;
        } else {
            #pragma unroll
            for (int i = 0; i < 8; i++)
                av[i] = (k0 + i < INS) ? xrow[k0 + i] : 0.f;
        }
    };
    loadA(0);

    for (int ks = 0; ks < KP / 32; ks++) {
        short8 bh[6], bl[6];
        #pragma unroll
        for (int ni = 0; ni < 6; ni++) {
            const size_t off = (size_t)(wn + ni * 16 + lmf) * KP + ks * 32 + lk;
            bh[ni] = *(const short8*)(Whi + off);
            bl[ni] = *(const short8*)(Wlo + off);
        }

        __syncthreads();
        {
            union { unsigned short us[8]; uint4 q; } ph, pl;
            #pragma unroll
            for (int i = 0; i < 8; i++) {
                unsigned short h = f2bf(av[i]);
                ph.us[i] = h;
                pl.us[i] = f2bf(av[i] - bf2f(h));
            }
            *(uint4*)&Ah[srow][kq * 8] = ph.q;
            *(uint4*)&Al[srow][kq * 8] = pl.q;
        }
        if (ks + 1 < KP / 32) loadA(ks + 1);
        __syncthreads();

        short8 ah[4], al[4];
        #pragma unroll
        for (int mi = 0; mi < 4; mi++) {
            ah[mi] = *(const short8*)&Ah[wm + mi * 16 + lmf][lk];
            al[mi] = *(const short8*)&Al[wm + mi * 16 + lmf][lk];
        }
        #pragma unroll
        for (int ni = 0; ni < 6; ni++) {
            #pragma unroll
            for (int mi = 0; mi < 4; mi++) {
                acc[mi][ni] = __builtin_amdgcn_mfma_f32_16x16x32_bf16(ah[mi], bh[ni], acc[mi][ni], 0, 0, 0);
                acc[mi][ni] = __builtin_amdgcn_mfma_f32_16x16x32_bf16(ah[mi], bl[ni], acc[mi][ni], 0, 0, 0);
                acc[mi][ni] = __builtin_amdgcn_mfma_f32_16x16x32_bf16(al[mi], bh[ni], acc[mi][ni], 0, 0, 0);
            }
        }
    }

    const int crow = (lane >> 4) * 4;
    #pragma unroll
    for (int ni = 0; ni < 6; ni++) {
        const int col = wn + ni * 16 + lmf;
        const float bias = bih[col];
        #pragma unroll
        for (int mi = 0; mi < 4; mi++) {
            #pragma unroll
            for (int i = 0; i < 4; i++) {
                const size_t row = (size_t)(m0 + wm + mi * 16 + crow + i);
                const float val = acc[mi][ni][i] + bias;
                if (BF16OUT) ((unsigned short*)xg_out)[row * NG + col] = f2bf(val);
                else         ((float*)xg_out)[row * NG + col] = val;
            }
        }
    }
}

// ---------- Kernel B: MFMA recurrence ----------
// Issue-saturated regime (1 wave/SIMD: MfmaUtil+VALUBusy = 85%): this round
// cuts instruction count, not latency.
//  - z4 zero C-in: no per-step accumulator re-zeroing (was up to 48 movs).
//  - lo-plane MFMAs chained into the SAME accumulators: 6 chains x depth 8.
//    s = acc[0]+acc[1] = (hh+hl)*(Whi+Wlo) — includes hl*Wlo (tiny, MORE
//    accurate vs fp32 reference than the old 3-product sum).
//  - v_rcp_f32 (1 instr, 1ulp) replaces 3 full-precision div sequences.
// Pass-folded A rows: rows lm&3==1 carry h_lo => every quad's C regs 0/1 =
// (hh*W, hl*W); activation on lanes 0-31, one column per lane.
// hbuf plane stride 320B: conflict-free (r4: SQ_LDS_BANK_CONFLICT = 0).
template <bool BF16XG>
__launch_bounds__(256, 1)
__global__ void gru_mfma(const void* __restrict__ xg_in,
                         const float* __restrict__ Whh,
                         const float* __restrict__ bhh,
                         float* __restrict__ hstate,
                         int t0, int CT, int initial, int final_chunk,
                         const float* __restrict__ Wout,
                         const float* __restrict__ bout,
                         float* __restrict__ out)
{
    const int b    = blockIdx.x;
    const int tid  = threadIdx.x;
    const int w    = tid >> 6;
    const int lane = tid & 63;
    const int lm   = lane & 15;
    const int quad = lane >> 4;

    __shared__ alignas(16) unsigned short hbuf[2][2][160]; // [dbuf][hi/lo][j], 320B plane stride
    __shared__ float red[2 * HID];

    // wave w's N-tiles (16 gate-cols each): r: {2w,2w+1}, z: {8+2w,..}, n: {16+2w,..}
    const int mt0 = 2 * w, mt2 = 8 + 2 * w, mt4 = 16 + 2 * w;
    const int mts[6] = {mt0, mt0 + 1, mt2, mt2 + 1, mt4, mt4 + 1};

    // ---- persistent B fragments: B[k=32kt+quad*8+j][n=tile*16+lm] = Whh[n][k] ----
    short8 w_hi[6][4], w_lo[6][4];
    #pragma unroll
    for (int t = 0; t < 6; t++) {
        const float* wrow = Whh + (size_t)(mts[t] * 16 + lm) * HID + quad * 8;
        #pragma unroll
        for (int kt = 0; kt < 4; kt++) {
            float4 f0 = *(const float4*)(wrow + kt * 32);
            float4 f1 = *(const float4*)(wrow + kt * 32 + 4);
            float vv[8] = {f0.x, f0.y, f0.z, f0.w, f1.x, f1.y, f1.z, f1.w};
            short8 h8, l8;
            #pragma unroll
            for (int i = 0; i < 8; i++) {
                unsigned short h = f2bf(vv[i]);
                h8[i] = (short)h;
                l8[i] = (short)f2bf(vv[i] - bf2f(h));
            }
            w_hi[t][kt] = h8;
            w_lo[t][kt] = l8;
        }
    }

    // ---- per-activation-lane state: lanes 0-31 own jd = 32w + 16*quad + lm ----
    const int dq = quad & 1;                    // d index for lanes<32
    const int jd = w * 32 + 16 * dq + lm;
    float hprev = 0.f, bhr = 0.f, bhz = 0.f, bhn = 0.f, wo0 = 0.f, wo1 = 0.f;
    float nx0r = 0.f, nx0z = 0.f, nx0n = 0.f;   // xg for even steps
    float nx1r = 0.f, nx1z = 0.f, nx1n = 0.f;   // xg for odd steps
    const float* xgf = (const float*)xg_in;
    const unsigned short* xgb = (const unsigned short*)xg_in;

    if (lane < 32) {
        float h0 = initial ? 0.f : hstate[b * HID + jd];
        hprev = h0;
        bhr = bhh[jd]; bhz = bhh[HID + jd]; bhn = bhh[2 * HID + jd];
        wo0 = Wout[jd]; wo1 = Wout[HID + jd];
        unsigned short hh = f2bf(h0);
        hbuf[0][0][jd] = hh;
        hbuf[0][1][jd] = f2bf(h0 - bf2f(hh));
        const size_t nb0 = (size_t)b * CT * NG;
        const size_t nb1 = nb0 + NG;
        if (BF16XG) {
            nx0r = bf2f(xgb[nb0 + jd]); nx0z = bf2f(xgb[nb0 + HID + jd]); nx0n = bf2f(xgb[nb0 + 2 * HID + jd]);
            nx1r = bf2f(xgb[nb1 + jd]); nx1z = bf2f(xgb[nb1 + HID + jd]); nx1n = bf2f(xgb[nb1 + 2 * HID + jd]);
        } else {
            nx0r = xgf[nb0 + jd]; nx0z = xgf[nb0 + HID + jd]; nx0n = xgf[nb0 + 2 * HID + jd];
            nx1r = xgf[nb1 + jd]; nx1z = xgf[nb1 + HID + jd]; nx1n = xgf[nb1 + 2 * HID + jd];
        }
    }
    __syncthreads();

    // A-frag plane select: rows lm in {1,5,9,13} read h_lo, others h_hi
    const int psel = ((lm & 3) == 1) ? 1 : 0;

    const f32x4 z4 = {0.f, 0.f, 0.f, 0.f};     // loop-invariant zero C-in

// one GRU timestep; P = compile-time dbuf index, T = runtime step, NX* = its xg regs
#define GRU_STEP(P, T, NXR, NXZ, NXN)                                                             \
    {                                                                                             \
        short8 a2[4];                                                                             \
        _Pragma("unroll")                                                                         \
        for (int kt = 0; kt < 4; kt++)                                                            \
            a2[kt] = *(const short8*)&hbuf[P][psel][kt * 32 + quad * 8];                          \
        f32x4 acc[6];                                                                             \
        _Pragma("unroll")                                                                         \
        for (int t = 0; t < 6; t++)                                                               \
            acc[t] = __builtin_amdgcn_mfma_f32_16x16x32_bf16(a2[0], w_hi[t][0], z4, 0, 0, 0);     \
        _Pragma("unroll")                                                                         \
        for (int kt = 1; kt < 4; kt++) {                                                          \
            _Pragma("unroll")                                                                     \
            for (int t = 0; t < 6; t++)                                                           \
                acc[t] = __builtin_amdgcn_mfma_f32_16x16x32_bf16(a2[kt], w_hi[t][kt], acc[t], 0, 0, 0); \
        }                                                                                         \
        _Pragma("unroll")                                                                         \
        for (int kt = 0; kt < 4; kt++) {                                                          \
            _Pragma("unroll")                                                                     \
            for (int t = 0; t < 6; t++)                                                           \
                acc[t] = __builtin_amdgcn_mfma_f32_16x16x32_bf16(a2[kt], w_lo[t][kt], acc[t], 0, 0, 0); \
        }                                                                                         \
        if (lane < 32) {                                                                          \
            /* regs 0/1 of each quad = (hh*(Whi+Wlo), hl*(Whi+Wlo)) for col lm */                 \
            float s0 = acc[0][0] + acc[0][1];                                                     \
            float s1 = acc[1][0] + acc[1][1];                                                     \
            float s2 = acc[2][0] + acc[2][1];                                                     \
            float s3 = acc[3][0] + acc[3][1];                                                     \
            float s4 = acc[4][0] + acc[4][1];                                                     \
            float s5 = acc[5][0] + acc[5][1];                                                     \
            float hgr = (dq ? s1 : s0) + bhr;                                                     \
            float hgz = (dq ? s3 : s2) + bhz;                                                     \
            float hgn = (dq ? s5 : s4) + bhn;                                                     \
            float rg = __builtin_amdgcn_rcpf(1.f + __expf(-((NXR) + hgr)));                       \
            float zg = __builtin_amdgcn_rcpf(1.f + __expf(-((NXZ) + hgz)));                       \
            float nv = (NXN) + rg * hgn;                                                          \
            float e  = __expf(2.f * nv);                                                          \
            float ng = 1.f - 2.f * __builtin_amdgcn_rcpf(e + 1.f);                                \
            hprev = (1.f - zg) * ng + zg * hprev;                                                 \
            unsigned short hh = f2bf(hprev);                                                      \
            hbuf[1 - (P)][0][jd] = hh;                                                            \
            hbuf[1 - (P)][1][jd] = f2bf(hprev - bf2f(hh));                                        \
            if ((T) + 2 < CT) {   /* prefetch distance 2; stays in flight across barriers */      \
                const size_t nb = ((size_t)b * CT + (T) + 2) * NG;                                \
                if (BF16XG) { NXR = bf2f(xgb[nb + jd]); NXZ = bf2f(xgb[nb + HID + jd]); NXN = bf2f(xgb[nb + 2 * HID + jd]); } \
                else        { NXR = xgf[nb + jd];       NXZ = xgf[nb + HID + jd];       NXN = xgf[nb + 2 * HID + jd]; }       \
            }                                                                                     \
        }                                                                                         \
        asm volatile("s_waitcnt lgkmcnt(0)\ns_barrier" ::: "memory");                             \
    }

    for (int tt = 0; tt < CT; tt += 2) {      // CT is a power of two >= 64
        GRU_STEP(0, tt,     nx0r, nx0z, nx0n)
        GRU_STEP(1, tt + 1, nx1r, nx1z, nx1n)
    }
#undef GRU_STEP

    if (lane < 32) hstate[b * HID + jd] = hprev;

    // ---- head: relu -> 2-class linear -> log_softmax (identical reduction tree) ----
    if (final_chunk) {
        if (lane < 32) {
            float f = hprev > 0.f ? hprev : 0.f;
            red[jd] = f * wo0;
            red[HID + jd] = f * wo1;
        }
        __syncthreads();
        if (tid < 64) {
            float l0 = red[tid] + red[64 + tid];
            float l1 = red[HID + tid] + red[HID + 64 + tid];
            #pragma unroll
            for (int d = 32; d > 0; d >>= 1) {
                l0 += __shfl_down(l0, d, 64);
                l1 += __shfl_down(l1, d, 64);
            }
            if (tid == 0) {
                l0 += bout[0]; l1 += bout[1];
                float m = fmaxf(l0, l1);
                float lse = m + logf(__expf(l0 - m) + __expf(l1 - m));
                out[b * 2 + 0] = l0 - lse;
                out[b * 2 + 1] = l1 - lse;
            }
        }
    }
}

// ---------- launch ----------
extern "C" void kernel_launch(void* const* d_in, const int* in_sizes, int n_in,
                              void* d_out, int out_size, void* d_ws, size_t ws_size,
                              hipStream_t stream) {
    const float* x    = (const float*)d_in[0];
    const float* Wih  = (const float*)d_in[1];
    const float* Whh  = (const float*)d_in[2];
    const float* bih  = (const float*)d_in[3];
    const float* bhh  = (const float*)d_in[4];
    const float* Wout = (const float*)d_in[5];
    const float* bout = (const float*)d_in[6];
    float* out = (float*)d_out;

    // ws layout: [W_hi | W_lo | hstate | xg]
    unsigned short* Whi = (unsigned short*)d_ws;                       // 384*320*2 = 245760 B
    unsigned short* Wlo = (unsigned short*)((char*)d_ws + 245760);
    float* hstate = (float*)((char*)d_ws + 491520);                    // 128 KiB
    void*  xg     = (void*)((char*)d_ws + 622592);
    const size_t avail = ws_size > 622592 ? ws_size - 622592 : 0;

    bool bf16;
    int CT;
    if (avail >= (size_t)BATCH * SEQ * NG * 4) {        // fp32 xg (201 MB)
        bf16 = false; CT = SEQ;
    } else if (avail >= (size_t)BATCH * SEQ * NG * 2) { // bf16 xg (100 MB)
        bf16 = true;  CT = SEQ;
    } else {                                            // chunked bf16
        bf16 = true;
        CT = 64;
        while (CT * 2 <= SEQ && avail >= (size_t)BATCH * (size_t)(CT * 2) * NG * 2) CT *= 2;
    }

    conv_wih<<<(NG * KP + 255) / 256, 256, 0, stream>>>(Wih, Whi, Wlo);

    for (int t0 = 0; t0 < SEQ; t0 += CT) {
        dim3 gridA((BATCH * CT) / 128);
        const int initial = (t0 == 0);
        const int final_chunk = (t0 + CT >= SEQ);
        if (bf16) {
            xg_fused<true><<<gridA, 512, 0, stream>>>(x, Whi, Wlo, bih, xg, t0, CT);
            gru_mfma<true><<<BATCH, 256, 0, stream>>>(xg, Whh, bhh, hstate, t0, CT,
                                                      initial, final_chunk, Wout, bout, out);
        } else {
            xg_fused<false><<<gridA, 512, 0, stream>>>(x, Whi, Wlo, bih, xg, t0, CT);
            gru_mfma<false><<<BATCH, 256, 0, stream>>>(xg, Whh, bhh, hstate, t0, CT,
                                                       initial, final_chunk, Wout, bout, out);
        }
    }
}

// Round 7
// 636.115 us; speedup vs baseline: 1.3119x; 1.0245x over previous
//
#include <hip/hip_runtime.h>
#include <hip/hip_bf16.h>
#include <math.h>

#define BATCH 256
#define SEQ   512
#define INS   300
#define KP    320   // K padded to 10 x 32 (xg gemm)
#define HID   128
#define NG    384   // 3*HID

typedef __attribute__((ext_vector_type(8))) short short8;   // 8 x bf16 (4 VGPRs)
typedef __attribute__((ext_vector_type(4))) float f32x4;

// ---------- helpers ----------
__device__ __forceinline__ float bf2f(unsigned short u) {
    unsigned int v = ((unsigned int)u) << 16;
    return __uint_as_float(v);
}
__device__ __forceinline__ unsigned short f2bf(float f) {
    unsigned int u = __float_as_uint(f);
    unsigned int r = (u + 0x7FFFu + ((u >> 16) & 1u)) >> 16;
    return (unsigned short)r;
}

// ---------- Kernel 0: split W_ih (fp32 384x300) -> bf16 hi/lo planes (384x320, k-padded) ----------
__global__ void conv_wih(const float* __restrict__ Wih,
                         unsigned short* __restrict__ Whi,
                         unsigned short* __restrict__ Wlo)
{
    int idx = blockIdx.x * 256 + threadIdx.x;     // 0 .. 384*320-1
    if (idx >= NG * KP) return;
    int g = idx / KP, k = idx - g * KP;
    float v = (k < INS) ? Wih[g * INS + k] : 0.f;
    unsigned short h = f2bf(v);
    float r = v - bf2f(h);
    Whi[idx] = h;
    Wlo[idx] = f2bf(r);
}

// ---------- Kernel A: fused single-N-pass xg = x @ W_ih^T + b_ih (unchanged) ----------
template <bool BF16OUT>
__launch_bounds__(512, 2)
__global__ void xg_fused(const float* __restrict__ x,
                         const unsigned short* __restrict__ Whi,
                         const unsigned short* __restrict__ Wlo,
                         const float* __restrict__ bih,
                         void* __restrict__ xg_out,
                         int t0, int CT)
{
    __shared__ unsigned short Ah[128][40], Al[128][40];   // 20 KiB

    const int tid  = threadIdx.x;
    const int lane = tid & 63;
    const int w    = tid >> 6;          // 0..7
    const int wm   = (w & 1) * 64;      // M half
    const int wn   = (w >> 1) * 96;     // N quarter
    const int m0   = blockIdx.x * 128;

    const int srow = tid >> 2;          // 0..127
    const int kq   = tid & 3;           // 0..3
    const int rr = m0 + srow;
    const int bb = rr / CT;
    const float* xrow = x + (size_t)(bb * SEQ + t0 + (rr - bb * CT)) * INS;

    const int lmf = lane & 15;
    const int lk  = (lane >> 4) * 8;

    f32x4 acc[4][6] = {};

    float av[8];
    auto loadA = [&](int ks) {
        const int k0 = ks * 32 + kq * 8;
        if (k0 + 8 <= INS) {
            float4 f0 = *(const float4*)(xrow + k0);
            float4 f1 = *(const float4*)(xrow + k0 + 4);
            av[0] = f0.x; av[1] = f0.y; av[2] = f0.z; av[3] = f0.w;
            av[4] = f1.x; av[5] = f1.y; av[6] = f1.z; av[7] = f1.w;
        } else {
            #pragma unroll
            for (int i = 0; i < 8; i++)
                av[i] = (k0 + i < INS) ? xrow[k0 + i] : 0.f;
        }
    };
    loadA(0);

    for (int ks = 0; ks < KP / 32; ks++) {
        short8 bh[6], bl[6];
        #pragma unroll
        for (int ni = 0; ni < 6; ni++) {
            const size_t off = (size_t)(wn + ni * 16 + lmf) * KP + ks * 32 + lk;
            bh[ni] = *(const short8*)(Whi + off);
            bl[ni] = *(const short8*)(Wlo + off);
        }

        __syncthreads();
        {
            union { unsigned short us[8]; uint4 q; } ph, pl;
            #pragma unroll
            for (int i = 0; i < 8; i++) {
                unsigned short h = f2bf(av[i]);
                ph.us[i] = h;
                pl.us[i] = f2bf(av[i] - bf2f(h));
            }
            *(uint4*)&Ah[srow][kq * 8] = ph.q;
            *(uint4*)&Al[srow][kq * 8] = pl.q;
        }
        if (ks + 1 < KP / 32) loadA(ks + 1);
        __syncthreads();

        short8 ah[4], al[4];
        #pragma unroll
        for (int mi = 0; mi < 4; mi++) {
            ah[mi] = *(const short8*)&Ah[wm + mi * 16 + lmf][lk];
            al[mi] = *(const short8*)&Al[wm + mi * 16 + lmf][lk];
        }
        #pragma unroll
        for (int ni = 0; ni < 6; ni++) {
            #pragma unroll
            for (int mi = 0; mi < 4; mi++) {
                acc[mi][ni] = __builtin_amdgcn_mfma_f32_16x16x32_bf16(ah[mi], bh[ni], acc[mi][ni], 0, 0, 0);
                acc[mi][ni] = __builtin_amdgcn_mfma_f32_16x16x32_bf16(ah[mi], bl[ni], acc[mi][ni], 0, 0, 0);
                acc[mi][ni] = __builtin_amdgcn_mfma_f32_16x16x32_bf16(al[mi], bh[ni], acc[mi][ni], 0, 0, 0);
            }
        }
    }

    const int crow = (lane >> 4) * 4;
    #pragma unroll
    for (int ni = 0; ni < 6; ni++) {
        const int col = wn + ni * 16 + lmf;
        const float bias = bih[col];
        #pragma unroll
        for (int mi = 0; mi < 4; mi++) {
            #pragma unroll
            for (int i = 0; i < 4; i++) {
                const size_t row = (size_t)(m0 + wm + mi * 16 + crow + i);
                const float val = acc[mi][ni][i] + bias;
                if (BF16OUT) ((unsigned short*)xg_out)[row * NG + col] = f2bf(val);
                else         ((float*)xg_out)[row * NG + col] = val;
            }
        }
    }
}

// ---------- Kernel B: MFMA recurrence, 8 waves (2/SIMD) ----------
// r6 counters: 1 wave/SIMD => MfmaUtil(50)+VALUBusy(32) ADD to 82% of issue.
// m114: MFMA-wave + VALU-wave on one SIMD co-schedule fully (time=max,not sum).
// => 8 waves x 3 tiles {w, 8+w, 16+w} (48 cols each), 24 MFMA/step/wave.
// Per-SIMD MFMA work unchanged (2x24); two waves interleave so one wave's
// activation/LDS/barrier hides under the other's MFMAs. B-frags halve to
// 96 VGPR/wave -> fits 2 waves/SIMD. Per-j chain order identical to r6
// (kt0-3 hi then kt0-3 lo, same accumulator) -> bitwise-identical output.
// hbuf plane stride 320B: conflict-free. Activation: lanes 0-15, j=16w+lm.
template <bool BF16XG>
__launch_bounds__(512, 2)
__global__ void gru_mfma(const void* __restrict__ xg_in,
                         const float* __restrict__ Whh,
                         const float* __restrict__ bhh,
                         float* __restrict__ hstate,
                         int t0, int CT, int initial, int final_chunk,
                         const float* __restrict__ Wout,
                         const float* __restrict__ bout,
                         float* __restrict__ out)
{
    const int b    = blockIdx.x;
    const int tid  = threadIdx.x;
    const int w    = tid >> 6;          // 0..7
    const int lane = tid & 63;
    const int lm   = lane & 15;
    const int quad = lane >> 4;

    __shared__ alignas(16) unsigned short hbuf[2][2][160]; // [dbuf][hi/lo][j], 320B plane stride
    __shared__ float red[2 * HID];

    // wave w's 3 N-tiles (16 gate-cols each): r: w, z: 8+w, n: 16+w
    const int mts[3] = {w, 8 + w, 16 + w};

    // ---- persistent B fragments: B[k=32kt+quad*8+j][n=tile*16+lm] = Whh[n][k] ----
    short8 w_hi[3][4], w_lo[3][4];
    #pragma unroll
    for (int t = 0; t < 3; t++) {
        const float* wrow = Whh + (size_t)(mts[t] * 16 + lm) * HID + quad * 8;
        #pragma unroll
        for (int kt = 0; kt < 4; kt++) {
            float4 f0 = *(const float4*)(wrow + kt * 32);
            float4 f1 = *(const float4*)(wrow + kt * 32 + 4);
            float vv[8] = {f0.x, f0.y, f0.z, f0.w, f1.x, f1.y, f1.z, f1.w};
            short8 h8, l8;
            #pragma unroll
            for (int i = 0; i < 8; i++) {
                unsigned short h = f2bf(vv[i]);
                h8[i] = (short)h;
                l8[i] = (short)f2bf(vv[i] - bf2f(h));
            }
            w_hi[t][kt] = h8;
            w_lo[t][kt] = l8;
        }
    }

    // ---- per-activation-lane state: lanes 0-15 of wave w own j = 16w + lm ----
    const int jd = w * 16 + lm;
    float hprev = 0.f, bhr = 0.f, bhz = 0.f, bhn = 0.f, wo0 = 0.f, wo1 = 0.f;
    float nx0r = 0.f, nx0z = 0.f, nx0n = 0.f;   // xg for even steps
    float nx1r = 0.f, nx1z = 0.f, nx1n = 0.f;   // xg for odd steps
    const float* xgf = (const float*)xg_in;
    const unsigned short* xgb = (const unsigned short*)xg_in;

    if (lane < 16) {
        float h0 = initial ? 0.f : hstate[b * HID + jd];
        hprev = h0;
        bhr = bhh[jd]; bhz = bhh[HID + jd]; bhn = bhh[2 * HID + jd];
        wo0 = Wout[jd]; wo1 = Wout[HID + jd];
        unsigned short hh = f2bf(h0);
        hbuf[0][0][jd] = hh;
        hbuf[0][1][jd] = f2bf(h0 - bf2f(hh));
        const size_t nb0 = (size_t)b * CT * NG;
        const size_t nb1 = nb0 + NG;
        if (BF16XG) {
            nx0r = bf2f(xgb[nb0 + jd]); nx0z = bf2f(xgb[nb0 + HID + jd]); nx0n = bf2f(xgb[nb0 + 2 * HID + jd]);
            nx1r = bf2f(xgb[nb1 + jd]); nx1z = bf2f(xgb[nb1 + HID + jd]); nx1n = bf2f(xgb[nb1 + 2 * HID + jd]);
        } else {
            nx0r = xgf[nb0 + jd]; nx0z = xgf[nb0 + HID + jd]; nx0n = xgf[nb0 + 2 * HID + jd];
            nx1r = xgf[nb1 + jd]; nx1z = xgf[nb1 + HID + jd]; nx1n = xgf[nb1 + 2 * HID + jd];
        }
    }
    __syncthreads();

    // A-frag plane select: rows lm in {1,5,9,13} read h_lo, others h_hi
    // => every quad's C regs 0/1 = (hh*W, hl*W) for its col lm
    const int psel = ((lm & 3) == 1) ? 1 : 0;

    const f32x4 z4 = {0.f, 0.f, 0.f, 0.f};     // loop-invariant zero C-in

// one GRU timestep; P = compile-time dbuf index, T = runtime step, NX* = its xg regs
#define GRU_STEP(P, T, NXR, NXZ, NXN)                                                             \
    {                                                                                             \
        short8 a2[4];                                                                             \
        _Pragma("unroll")                                                                         \
        for (int kt = 0; kt < 4; kt++)                                                            \
            a2[kt] = *(const short8*)&hbuf[P][psel][kt * 32 + quad * 8];                          \
        f32x4 acc[3];                                                                             \
        _Pragma("unroll")                                                                         \
        for (int t = 0; t < 3; t++)                                                               \
            acc[t] = __builtin_amdgcn_mfma_f32_16x16x32_bf16(a2[0], w_hi[t][0], z4, 0, 0, 0);     \
        _Pragma("unroll")                                                                         \
        for (int kt = 1; kt < 4; kt++) {                                                          \
            _Pragma("unroll")                                                                     \
            for (int t = 0; t < 3; t++)                                                           \
                acc[t] = __builtin_amdgcn_mfma_f32_16x16x32_bf16(a2[kt], w_hi[t][kt], acc[t], 0, 0, 0); \
        }                                                                                         \
        _Pragma("unroll")                                                                         \
        for (int kt = 0; kt < 4; kt++) {                                                          \
            _Pragma("unroll")                                                                     \
            for (int t = 0; t < 3; t++)                                                           \
                acc[t] = __builtin_amdgcn_mfma_f32_16x16x32_bf16(a2[kt], w_lo[t][kt], acc[t], 0, 0, 0); \
        }                                                                                         \
        if (lane < 16) {                                                                          \
            /* regs 0/1 = (hh*(Whi+Wlo), hl*(Whi+Wlo)) for col lm of each tile */                 \
            float hgr = (acc[0][0] + acc[0][1]) + bhr;                                            \
            float hgz = (acc[1][0] + acc[1][1]) + bhz;                                            \
            float hgn = (acc[2][0] + acc[2][1]) + bhn;                                            \
            float rg = __builtin_amdgcn_rcpf(1.f + __expf(-((NXR) + hgr)));                       \
            float zg = __builtin_amdgcn_rcpf(1.f + __expf(-((NXZ) + hgz)));                       \
            float nv = (NXN) + rg * hgn;                                                          \
            float e  = __expf(2.f * nv);                                                          \
            float ng = 1.f - 2.f * __builtin_amdgcn_rcpf(e + 1.f);                                \
            hprev = (1.f - zg) * ng + zg * hprev;                                                 \
            unsigned short hh = f2bf(hprev);                                                      \
            hbuf[1 - (P)][0][jd] = hh;                                                            \
            hbuf[1 - (P)][1][jd] = f2bf(hprev - bf2f(hh));                                        \
            if ((T) + 2 < CT) {   /* prefetch distance 2; stays in flight across barriers */      \
                const size_t nb = ((size_t)b * CT + (T) + 2) * NG;                                \
                if (BF16XG) { NXR = bf2f(xgb[nb + jd]); NXZ = bf2f(xgb[nb + HID + jd]); NXN = bf2f(xgb[nb + 2 * HID + jd]); } \
                else        { NXR = xgf[nb + jd];       NXZ = xgf[nb + HID + jd];       NXN = xgf[nb + 2 * HID + jd]; }       \
            }                                                                                     \
        }                                                                                         \
        asm volatile("s_waitcnt lgkmcnt(0)\ns_barrier" ::: "memory");                             \
    }

    for (int tt = 0; tt < CT; tt += 2) {      // CT is a power of two >= 64
        GRU_STEP(0, tt,     nx0r, nx0z, nx0n)
        GRU_STEP(1, tt + 1, nx1r, nx1z, nx1n)
    }
#undef GRU_STEP

    if (lane < 16) hstate[b * HID + jd] = hprev;

    // ---- head: relu -> 2-class linear -> log_softmax (identical reduction tree) ----
    if (final_chunk) {
        if (lane < 16) {
            float f = hprev > 0.f ? hprev : 0.f;
            red[jd] = f * wo0;
            red[HID + jd] = f * wo1;
        }
        __syncthreads();
        if (tid < 64) {
            float l0 = red[tid] + red[64 + tid];
            float l1 = red[HID + tid] + red[HID + 64 + tid];
            #pragma unroll
            for (int d = 32; d > 0; d >>= 1) {
                l0 += __shfl_down(l0, d, 64);
                l1 += __shfl_down(l1, d, 64);
            }
            if (tid == 0) {
                l0 += bout[0]; l1 += bout[1];
                float m = fmaxf(l0, l1);
                float lse = m + logf(__expf(l0 - m) + __expf(l1 - m));
                out[b * 2 + 0] = l0 - lse;
                out[b * 2 + 1] = l1 - lse;
            }
        }
    }
}

// ---------- launch ----------
extern "C" void kernel_launch(void* const* d_in, const int* in_sizes, int n_in,
                              void* d_out, int out_size, void* d_ws, size_t ws_size,
                              hipStream_t stream) {
    const float* x    = (const float*)d_in[0];
    const float* Wih  = (const float*)d_in[1];
    const float* Whh  = (const float*)d_in[2];
    const float* bih  = (const float*)d_in[3];
    const float* bhh  = (const float*)d_in[4];
    const float* Wout = (const float*)d_in[5];
    const float* bout = (const float*)d_in[6];
    float* out = (float*)d_out;

    // ws layout: [W_hi | W_lo | hstate | xg]
    unsigned short* Whi = (unsigned short*)d_ws;                       // 384*320*2 = 245760 B
    unsigned short* Wlo = (unsigned short*)((char*)d_ws + 245760);
    float* hstate = (float*)((char*)d_ws + 491520);                    // 128 KiB
    void*  xg     = (void*)((char*)d_ws + 622592);
    const size_t avail = ws_size > 622592 ? ws_size - 622592 : 0;

    bool bf16;
    int CT;
    if (avail >= (size_t)BATCH * SEQ * NG * 4) {        // fp32 xg (201 MB)
        bf16 = false; CT = SEQ;
    } else if (avail >= (size_t)BATCH * SEQ * NG * 2) { // bf16 xg (100 MB)
        bf16 = true;  CT = SEQ;
    } else {                                            // chunked bf16
        bf16 = true;
        CT = 64;
        while (CT * 2 <= SEQ && avail >= (size_t)BATCH * (size_t)(CT * 2) * NG * 2) CT *= 2;
    }

    conv_wih<<<(NG * KP + 255) / 256, 256, 0, stream>>>(Wih, Whi, Wlo);

    for (int t0 = 0; t0 < SEQ; t0 += CT) {
        dim3 gridA((BATCH * CT) / 128);
        const int initial = (t0 == 0);
        const int final_chunk = (t0 + CT >= SEQ);
        if (bf16) {
            xg_fused<true><<<gridA, 512, 0, stream>>>(x, Whi, Wlo, bih, xg, t0, CT);
            gru_mfma<true><<<BATCH, 512, 0, stream>>>(xg, Whh, bhh, hstate, t0, CT,
                                                      initial, final_chunk, Wout, bout, out);
        } else {
            xg_fused<false><<<gridA, 512, 0, stream>>>(x, Whi, Wlo, bih, xg, t0, CT);
            gru_mfma<false><<<BATCH, 512, 0, stream>>>(xg, Whh, bhh, hstate, t0, CT,
                                                       initial, final_chunk, Wout, bout, out);
        }
    }
}